// Round 18
// baseline (693.646 us; speedup 1.0000x reference)
//
#include <hip/hip_runtime.h>
#include <hip/hip_bf16.h>
#include <math.h>

#define BATCH 1024

typedef __attribute__((ext_vector_type(8))) short bf16x8;
typedef __attribute__((ext_vector_type(4))) float f32x4;

// Padded NHWC activation geometry, ci-chunk-major rows:
//   addr = img*IMG_B + row*ROW_B + chunk*CH_B + px*16
// (chunk = ci-group of 8 bf16; 34 px * 16 B = 544 B per chunk-plane; 8 planes/row)
#define IMG_ELEMS 73984
#define IMG_B 147968
#define ROW_B 4352            // 34 px * 128 B
#define CH_B 544              // 34 px * 16 B
#define WT_OFF 43520          // LDS offset of staged weights (after 10 act rows)
#define WT_HALF_B 36864       // one co-half weight image: 9 taps x 2 kb x 2 nt x 4 q x 16 m x 16 B

// ---------------- LeNet conv1 (3->6, 5x5 VALID) + ReLU + 2x2 maxpool ----------------
__global__ __launch_bounds__(256) void lenet_conv1(const float* __restrict__ x,
    const float* __restrict__ w, const float* __restrict__ bias, float* __restrict__ p1)
{
    __shared__ float img[3 * 1024];
    __shared__ float wl[450];
    __shared__ float bl[6];
    int b = blockIdx.x, t = threadIdx.x;
    for (int i = t; i < 3072; i += 256) img[i] = x[(size_t)b * 3072 + i];
    for (int i = t; i < 450; i += 256) wl[i] = w[i];
    if (t < 6) bl[t] = bias[t];
    __syncthreads();
    for (int idx = t; idx < 1176; idx += 256) {
        int o = idx / 196, r = idx - o * 196, py = r / 14, px = r - py * 14;
        int y0 = 2 * py, x0 = 2 * px;
        float s00, s01, s10, s11;
        s00 = s01 = s10 = s11 = bl[o];
        for (int c = 0; c < 3; c++) {
            float pv[6][6];
            #pragma unroll
            for (int i2 = 0; i2 < 6; i2++)
                #pragma unroll
                for (int j2 = 0; j2 < 6; j2++)
                    pv[i2][j2] = img[c * 1024 + (y0 + i2) * 32 + x0 + j2];
            const float* wc = &wl[o * 75 + c * 25];
            #pragma unroll
            for (int ky = 0; ky < 5; ky++)
                #pragma unroll
                for (int kx = 0; kx < 5; kx++) {
                    float wv = wc[ky * 5 + kx];
                    s00 += pv[ky][kx] * wv;
                    s01 += pv[ky][kx + 1] * wv;
                    s10 += pv[ky + 1][kx] * wv;
                    s11 += pv[ky + 1][kx + 1] * wv;
                }
        }
        float m = fmaxf(fmaxf(s00, s01), fmaxf(s10, s11));
        p1[(size_t)b * 1176 + idx] = fmaxf(m, 0.f);
    }
}

// ---------------- LeNet conv2 (6->16, 5x5 VALID) + ReLU + 2x2 maxpool ----------------
__global__ __launch_bounds__(256) void lenet_conv2(const float* __restrict__ p1,
    const float* __restrict__ w, const float* __restrict__ bias, float* __restrict__ p2)
{
    __shared__ float img[1176];
    __shared__ float wl[2400];
    __shared__ float bl[16];
    int b = blockIdx.x, t = threadIdx.x;
    for (int i = t; i < 1176; i += 256) img[i] = p1[(size_t)b * 1176 + i];
    for (int i = t; i < 2400; i += 256) wl[i] = w[i];
    if (t < 16) bl[t] = bias[t];
    __syncthreads();
    for (int idx = t; idx < 400; idx += 256) {
        int o = idx / 25, r = idx - o * 25, py = r / 5, px = r - py * 5;
        int y0 = 2 * py, x0 = 2 * px;
        float s00, s01, s10, s11;
        s00 = s01 = s10 = s11 = bl[o];
        for (int c = 0; c < 6; c++) {
            float pv[6][6];
            #pragma unroll
            for (int i2 = 0; i2 < 6; i2++)
                #pragma unroll
                for (int j2 = 0; j2 < 6; j2++)
                    pv[i2][j2] = img[c * 196 + (y0 + i2) * 14 + x0 + j2];
            const float* wc = &wl[o * 150 + c * 25];
            #pragma unroll
            for (int ky = 0; ky < 5; ky++)
                #pragma unroll
                for (int kx = 0; kx < 5; kx++) {
                    float wv = wc[ky * 5 + kx];
                    s00 += pv[ky][kx] * wv;
                    s01 += pv[ky][kx + 1] * wv;
                    s10 += pv[ky + 1][kx] * wv;
                    s11 += pv[ky + 1][kx + 1] * wv;
                }
        }
        float m = fmaxf(fmaxf(s00, s01), fmaxf(s10, s11));
        p2[(size_t)b * 400 + idx] = fmaxf(m, 0.f);
    }
}

// ---------------- LeNet FC head + argmax + conf-matrix + low-conf flag ----------------
__global__ __launch_bounds__(256) void lenet_fc(const float* __restrict__ p2,
    const float* __restrict__ w1, const float* __restrict__ b1,
    const float* __restrict__ w2, const float* __restrict__ b2,
    const float* __restrict__ w3, const float* __restrict__ b3,
    const int* __restrict__ labels, const float* __restrict__ thr,
    float* __restrict__ out, float* __restrict__ conf, int* __restrict__ flags)
{
    __shared__ float xin[400];
    __shared__ float h1[120];
    __shared__ float h2[84];
    __shared__ float ps[256];
    __shared__ float lg[10];
    int b = blockIdx.x, t = threadIdx.x;
    for (int i = t; i < 400; i += 256) xin[i] = p2[(size_t)b * 400 + i];
    __syncthreads();
    {
        int n = t & 127, half = t >> 7;
        float s = 0.f;
        if (n < 120) {
            int k0 = half * 200;
            for (int k = k0; k < k0 + 200; k++) s += xin[k] * w1[k * 120 + n];
        }
        ps[t] = s;
    }
    __syncthreads();
    if (t < 120) h1[t] = fmaxf(ps[t] + ps[t + 128] + b1[t], 0.f);
    __syncthreads();
    {
        int n = t & 127, half = t >> 7;
        float s = 0.f;
        if (n < 84) {
            int k0 = half * 60;
            for (int k = k0; k < k0 + 60; k++) s += h1[k] * w2[k * 84 + n];
        }
        ps[t] = s;
    }
    __syncthreads();
    if (t < 84) h2[t] = fmaxf(ps[t] + ps[t + 128] + b2[t], 0.f);
    __syncthreads();
    if (t < 10) {
        float s = b3[t];
        for (int k = 0; k < 84; k++) s += h2[k] * w3[k * 10 + t];
        lg[t] = s;
        out[(size_t)b * 10 + t] = s;
    }
    __syncthreads();
    if (t == 0) {
        int pred = 0;
        float m = lg[0];
        #pragma unroll
        for (int j = 1; j < 10; j++) if (lg[j] > m) { m = lg[j]; pred = j; }
        float se = 0.f, m2 = -1e30f;
        #pragma unroll
        for (int j = 0; j < 10; j++) {
            se += expf(lg[j] - m);
            if (j != pred) m2 = fmaxf(m2, lg[j]);
        }
        float gap = (1.f - expf(m2 - m)) / se;
        flags[b] = (gap <= thr[0]) ? 1 : 0;
        atomicAdd(&conf[labels[b] * 10 + pred], 1.f);
    }
}

// ---------------- weight prep: 4x OIHW fp32 -> bf16 LDS image [nh][tap][kb][nt][q][m][e] ----------------
__global__ __launch_bounds__(256) void prep_weights(
    const float* __restrict__ w0, const float* __restrict__ w1,
    const float* __restrict__ w2, const float* __restrict__ w3,
    __hip_bfloat16* __restrict__ dst)
{
    int tid = blockIdx.x * 256 + threadIdx.x;
    if (tid >= 4 * 36864) return;
    int c = tid / 36864, r = tid - c * 36864;
    int tap = r / 4096, r2 = r - tap * 4096;
    int co = r2 >> 6, ci = r2 & 63;
    const float* src = (c == 0) ? w0 : (c == 1) ? w1 : (c == 2) ? w2 : w3;
    float v = src[((size_t)co * 64 + ci) * 9 + tap];
    int nh = co >> 5, nt = (co >> 4) & 1, m = co & 15;
    int kb = ci >> 5, q = (ci >> 3) & 3, e = ci & 7;
    size_t elem = (size_t)(c * 2 + nh) * 18432
                + (size_t)((tap * 2 + kb) * 2 + nt) * 512 + q * 128 + m * 8 + e;
    dst[elem] = __float2bfloat16(v);
}

// ---------------- conv0 weight transpose: OIHW fp32 [64][3][3][3] -> [k 27][co 64] fp32 ----------------
__global__ __launch_bounds__(256) void prep_w0t(const float* __restrict__ w,
                                                float* __restrict__ dst)
{
    int tid = blockIdx.x * 256 + threadIdx.x;
    if (tid >= 1728) return;
    int k = tid >> 6, co = tid & 63;
    dst[tid] = w[co * 27 + k];
}

// ---------------- zero pad borders of [n] padded images (chunk-major layout) ----------------
__global__ __launch_bounds__(256) void zero_borders(__hip_bfloat16* __restrict__ buf, int n)
{
    int tid = blockIdx.x * 256 + threadIdx.x;
    int total = n * 132 * 8;
    if (tid >= total) return;
    int img = tid / 1056, r = tid - img * 1056;
    int pxi = r >> 3, chunk = r & 7;
    int row, col;
    if (pxi < 34)       { row = 0;  col = pxi; }
    else if (pxi < 68)  { row = 33; col = pxi - 34; }
    else if (pxi < 100) { row = pxi - 67; col = 0; }
    else                { row = pxi - 99; col = 33; }
    uint4 z = {0, 0, 0, 0};
    *(uint4*)((char*)buf + (size_t)img * IMG_B + (size_t)row * ROW_B
              + chunk * CH_B + col * 16) = z;
}

// ---------------- conv0: NCHW fp32 [3][32][32] -> padded chunk-major bf16, bias+ReLU ----------------
// r9-verified body: k-major inner loop, 64 independent accumulators; wave-
// uniform s_load weights; full-row LDS bounce -> one contiguous 34816-B store.
// Strip-fastest task order + bijective XCD swizzle (r17).
__global__ __launch_bounds__(256) void conv0_nhwc(const float* __restrict__ x,
    const float* __restrict__ wT, const float* __restrict__ bias,
    __hip_bfloat16* __restrict__ out, int cb)
{
    __shared__ char smem[8 * ROW_B];   // input tile (16320 B) then row bounce (34816 B)
    float* sl = (float*)smem;          // [3][10][34]
    int bid = blockIdx.x;
    int task = (bid & 7) * (gridDim.x >> 3) + (bid >> 3);   // bijective XCD swizzle
    int img = task >> 2, strip = task & 3;                  // strip fastest
    int r0 = strip * 8;
    int t = threadIdx.x;
    const float* xi = x + (size_t)img * 3072;
    for (int i = t; i < 1020; i += 256) {
        int c = i / 340, rr2 = i - c * 340;
        int rr = rr2 / 34, cc = rr2 - rr * 34;
        int y = r0 + rr - 1, xx = cc - 1;
        float v = 0.f;
        if (y >= 0 && y < 32 && xx >= 0 && xx < 32) v = xi[c * 1024 + y * 32 + xx];
        sl[(c * 10 + rr) * 34 + cc] = v;
    }
    __syncthreads();

    int rr = t >> 5, col = t & 31;
    float iv[27];
    #pragma unroll
    for (int c = 0; c < 3; c++)
        #pragma unroll
        for (int dy = 0; dy < 3; dy++)
            #pragma unroll
            for (int dx = 0; dx < 3; dx++)
                iv[c * 9 + dy * 3 + dx] = sl[(c * 10 + rr + dy) * 34 + col + dx];
    __syncthreads();   // all sl reads done; smem becomes the row bounce

    float s[64];
    #pragma unroll
    for (int co = 0; co < 64; co++) s[co] = bias[co];   // uniform s_load burst
    #pragma unroll
    for (int k = 0; k < 27; k++) {
        const float v = iv[k];
        const float* wk = wT + k * 64;                  // uniform -> s_load_dwordx16 x4
        #pragma unroll
        for (int co = 0; co < 64; co++) s[co] = fmaf(v, wk[co], s[co]);
    }
    __hip_bfloat16 ov[64];
    #pragma unroll
    for (int co = 0; co < 64; co++) ov[co] = __float2bfloat16(fmaxf(s[co], 0.f));

    // bounce: complete chunk-major rows (incl. pad cols as zeros)
    char* brow = smem + rr * ROW_B + (col + 1) * 16;
    const uint4* srcv = (const uint4*)ov;
    #pragma unroll
    for (int j = 0; j < 8; j++) *(uint4*)(brow + j * CH_B) = srcv[j];
    if (t < 128) {
        int row = t >> 4, ch = (t >> 1) & 7, side = t & 1;
        uint4 z = {0, 0, 0, 0};
        *(uint4*)(smem + row * ROW_B + ch * CH_B + (side ? 33 : 0) * 16) = z;
    }
    __syncthreads();
    // contiguous 34816-B store (rows r0+1 .. r0+8), fully line-covered
    char* gbase = (char*)out + (size_t)img * IMG_B + (size_t)(r0 + 1) * ROW_B;
    for (int u = t; u < 2176; u += 256)
        *(uint4*)(gbase + (size_t)u * 16) = *(const uint4*)(smem + (size_t)u * 16);
}

#define GLL(gp, lp)                                                            \
    __builtin_amdgcn_global_load_lds(                                          \
        (const __attribute__((address_space(1))) unsigned int*)(gp),           \
        (__attribute__((address_space(3))) unsigned int*)(lp), 16, 0, 0)

// ---------------- 3x3 SAME conv: LDS weights, SWAPPED MFMA, direct store ----------------
// r18 = r15/r17 conv body (best verified: 48.4 us/dispatch) + MODE template:
//   MODE 0: plain conv+bias+relu
//   MODE 1: + skip-add (residual)
//   MODE 2: + skip-add + fused global avg-pool accumulate (final layer only):
//           each lane sums its relu'd outputs over nt (2 rows x 2 px-halves),
//           __shfl_xor reduces over the 16 m-lanes (all 32 px), q-leader
//           atomicAdds 8 floats -> pool[img][co]. Eliminates res_head's
//           ~135 MB full-tensor re-read.
template<int MODE>
__global__ __launch_bounds__(256, 2) void conv3x3_lds(
    const __hip_bfloat16* __restrict__ act, const __hip_bfloat16* __restrict__ wts,
    const float* __restrict__ bias, const __hip_bfloat16* __restrict__ skip,
    __hip_bfloat16* __restrict__ out, float* __restrict__ pool, int cb)
{
    __shared__ char sl[WT_OFF + WT_HALF_B];   // 80384 B
    int bid = blockIdx.x;
    int task = (bid & 7) * (gridDim.x >> 3) + (bid >> 3);   // bijective XCD swizzle
    int img = task >> 3;
    int rem = task & 7;
    int strip = rem >> 1, nh = rem & 1;       // nh fastest: pair 2k/2k+1 adjacent
    int t = threadIdx.x;
    int w = t >> 6, lane = t & 63;
    int m = lane & 15, q = lane >> 4;

    // ---- stage 10 padded act rows (8s .. 8s+9), contiguous 43520 B ----
    const char* gsrc = (const char*)act + (size_t)img * IMG_B + (size_t)(strip * 8) * ROW_B;
    for (int u0 = w * 64; u0 < 2720; u0 += 256) {
        int u = u0 + lane;
        if (u < 2720)
            GLL(gsrc + (size_t)u * 16, sl + u0 * 16);
    }
    // ---- stage weight half, contiguous 36864 B (2304 units, exact) ----
    const char* gw = (const char*)wts + (size_t)nh * WT_HALF_B;
    for (int u0 = w * 64; u0 < 2304; u0 += 256)
        GLL(gw + (size_t)(u0 + lane) * 16, sl + WT_OFF + u0 * 16);
    __syncthreads();

    // ---- fragment base offsets (identical bytes to r9; roles swapped) ----
    int xbase[4];   // act frags (B-operand): nt -> row 2w+(nt>>1), px-half nt&1
    #pragma unroll
    for (int nt = 0; nt < 4; nt++)
        xbase[nt] = (2 * w + (nt >> 1)) * ROW_B + ((nt & 1) * 16 + m) * 16 + q * CH_B;
    int wbase[2];   // weight frags (A-operand): mt -> co block of 16
    #pragma unroll
    for (int mt = 0; mt < 2; mt++)
        wbase[mt] = WT_OFF + mt * 1024 + q * 256 + m * 16;

    f32x4 acc[2][4] = {};
    bf16x8 a[2][4], b[2][2];

    #define XLOAD(s, buf)                                                      \
        {                                                                      \
            const int tap_ = (s) >> 1, kb_ = (s) & 1;                          \
            const int off_ = (tap_ / 3) * ROW_B + (tap_ - (tap_ / 3) * 3) * 16 \
                           + kb_ * (4 * CH_B);                                 \
            _Pragma("unroll")                                                  \
            for (int nt = 0; nt < 4; nt++)                                     \
                a[buf][nt] = *(const bf16x8*)(sl + xbase[nt] + off_);          \
        }
    #define WLOAD(s, buf)                                                      \
        {                                                                      \
            const int off_ = ((s) >> 1) * 4096 + ((s) & 1) * 2048;             \
            _Pragma("unroll")                                                  \
            for (int mt = 0; mt < 2; mt++)                                     \
                b[buf][mt] = *(const bf16x8*)(sl + wbase[mt] + off_);          \
        }

    XLOAD(0, 0) WLOAD(0, 0)
    #pragma unroll
    for (int s = 0; s < 18; s++) {
        int cur = s & 1;
        if (s < 17) { XLOAD(s + 1, cur ^ 1) WLOAD(s + 1, cur ^ 1) }
        #pragma unroll
        for (int mt = 0; mt < 2; mt++)
            #pragma unroll
            for (int nt = 0; nt < 4; nt++)
                acc[mt][nt] = __builtin_amdgcn_mfma_f32_16x16x32_bf16(
                    b[cur][mt], a[cur][nt], acc[mt][nt], 0, 0, 0);
    }
    #undef XLOAD
    #undef WLOAD

    // ---- direct store: px = m + (nt&1)*16, co = nh*32 + mt*16 + q*4 + r ----
    // (r2-verified D layout; 4 consecutive co per lane = one aligned uint2)
    char* oimg = (char*)out + (size_t)img * IMG_B;
    const char* simg = (const char*)skip + (size_t)img * IMG_B;
    float4 bv4[2];
    #pragma unroll
    for (int mt = 0; mt < 2; mt++)
        bv4[mt] = *(const float4*)(bias + nh * 32 + mt * 16 + q * 4);

    size_t goff[2][4];
    #pragma unroll
    for (int mt = 0; mt < 2; mt++)
        #pragma unroll
        for (int nt = 0; nt < 4; nt++)
            goff[mt][nt] = (size_t)(strip * 8 + 1 + 2 * w + (nt >> 1)) * ROW_B
                         + (nh * 4 + 2 * mt + (q >> 1)) * CH_B
                         + (m + (nt & 1) * 16 + 1) * 16 + (q & 1) * 8;

    union { uint2 u; __hip_bfloat16 h[4]; } sk[2][4];
    if (MODE >= 1) {
        #pragma unroll
        for (int mt = 0; mt < 2; mt++)
            #pragma unroll
            for (int nt = 0; nt < 4; nt++)
                sk[mt][nt].u = *(const uint2*)(simg + goff[mt][nt]);
    }
    float psum[2][4];
    if (MODE == 2) {
        #pragma unroll
        for (int mt = 0; mt < 2; mt++)
            #pragma unroll
            for (int r = 0; r < 4; r++) psum[mt][r] = 0.f;
    }
    #pragma unroll
    for (int mt = 0; mt < 2; mt++) {
        #pragma unroll
        for (int nt = 0; nt < 4; nt++) {
            union { uint2 u; __hip_bfloat16 h[4]; } pk;
            #pragma unroll
            for (int r = 0; r < 4; r++) {
                float f = acc[mt][nt][r] + ((const float*)&bv4[mt])[r];
                if (MODE >= 1) f += __bfloat162float(sk[mt][nt].h[r]);
                f = fmaxf(f, 0.f);
                if (MODE == 2) psum[mt][r] += f;
                pk.h[r] = __float2bfloat16(f);
            }
            *(uint2*)(oimg + goff[mt][nt]) = pk.u;
        }
    }
    if (MODE == 2) {
        // reduce over the 16 m-lanes (covers all 32 px of this wave's 2 rows)
        #pragma unroll
        for (int mt = 0; mt < 2; mt++)
            #pragma unroll
            for (int r = 0; r < 4; r++) {
                float v = psum[mt][r];
                v += __shfl_xor(v, 1, 64);
                v += __shfl_xor(v, 2, 64);
                v += __shfl_xor(v, 4, 64);
                v += __shfl_xor(v, 8, 64);
                if (m == 0)
                    atomicAdd(&pool[img * 64 + nh * 32 + mt * 16 + q * 4 + r], v);
            }
    }
}

// ---------------- ResNet FC head: pooled [img][64] -> FC, masked merge ----------------
__global__ __launch_bounds__(64) void res_fc(const float* __restrict__ pool,
    const float* __restrict__ rfc, const float* __restrict__ rfb,
    const int* __restrict__ flags, float* __restrict__ out)
{
    __shared__ float mns[64];
    int img = blockIdx.x, t = threadIdx.x;
    mns[t] = pool[img * 64 + t] * (1.f / 1024.f);
    __syncthreads();
    if (t < 10 && flags[img]) {
        float s2 = rfb[t];
        for (int c = 0; c < 64; c++) s2 += mns[c] * rfc[c * 10 + t];
        out[(size_t)img * 10 + t] = s2;
    }
}

extern "C" void kernel_launch(void* const* d_in, const int* in_sizes, int n_in,
                              void* d_out, int out_size, void* d_ws, size_t ws_size,
                              hipStream_t stream)
{
    const float* x    = (const float*)d_in[0];
    const float* thr  = (const float*)d_in[1];
    const int*   labels = (const int*)d_in[2];
    const float* lw1 = (const float*)d_in[3];  const float* lb1 = (const float*)d_in[4];
    const float* lw2 = (const float*)d_in[5];  const float* lb2 = (const float*)d_in[6];
    const float* lfc1 = (const float*)d_in[7]; const float* lfb1 = (const float*)d_in[8];
    const float* lfc2 = (const float*)d_in[9]; const float* lfb2 = (const float*)d_in[10];
    const float* lfc3 = (const float*)d_in[11];const float* lfb3 = (const float*)d_in[12];
    const float* rw0 = (const float*)d_in[13]; const float* rb0 = (const float*)d_in[14];
    const float* rw1a = (const float*)d_in[15];const float* rb1a = (const float*)d_in[16];
    const float* rw1b = (const float*)d_in[17];const float* rb1b = (const float*)d_in[18];
    const float* rw2a = (const float*)d_in[19];const float* rb2a = (const float*)d_in[20];
    const float* rw2b = (const float*)d_in[21];const float* rb2b = (const float*)d_in[22];
    const float* rfc = (const float*)d_in[23]; const float* rfb = (const float*)d_in[24];

    float* out  = (float*)d_out;
    float* conf = out + (size_t)BATCH * 10;

    int nc = 1;
    while (nc < 16 &&
           2ull * (size_t)(BATCH / nc) * 147968ull + 294912ull + 16384ull
               + (size_t)(BATCH / nc) * 256ull > ws_size)
        nc <<= 1;
    int cb = BATCH / nc;

    __hip_bfloat16* A  = (__hip_bfloat16*)d_ws;
    __hip_bfloat16* Bb = A + (size_t)cb * IMG_ELEMS;
    __hip_bfloat16* wprep = Bb + (size_t)cb * IMG_ELEMS;
    int* flags = (int*)((char*)wprep + 294912);
    float* w0t = (float*)((char*)wprep + 294912 + 4096);
    float* pool = (float*)((char*)wprep + 294912 + 16384);   // cb*64 floats

    float* p1 = (float*)A;
    float* p2 = p1 + 1204224;

    hipMemsetAsync(conf, 0, 100 * sizeof(float), stream);

    prep_weights<<<(4 * 36864 + 255) / 256, 256, 0, stream>>>(rw1a, rw1b, rw2a, rw2b, wprep);
    prep_w0t<<<7, 256, 0, stream>>>(rw0, w0t);

    lenet_conv1<<<BATCH, 256, 0, stream>>>(x, lw1, lb1, p1);
    lenet_conv2<<<BATCH, 256, 0, stream>>>(p1, lw2, lb2, p2);
    lenet_fc<<<BATCH, 256, 0, stream>>>(p2, lfc1, lfb1, lfc2, lfb2, lfc3, lfb3,
                                        labels, thr, out, conf, flags);

    // single call covers BOTH contiguous image buffers (A and Bb)
    int zb = (2 * cb * 1056 + 255) / 256;
    zero_borders<<<zb, 256, 0, stream>>>(A, 2 * cb);

    const __hip_bfloat16* W1a = wprep;
    const __hip_bfloat16* W1b = wprep + 36864;
    const __hip_bfloat16* W2a = wprep + 2 * 36864;
    const __hip_bfloat16* W2b = wprep + 3 * 36864;

    for (int c0 = 0; c0 < BATCH; c0 += cb) {
        const float* xc = x + (size_t)c0 * 3072;
        hipMemsetAsync(pool, 0, (size_t)cb * 64 * sizeof(float), stream);
        conv0_nhwc<<<cb * 4, 256, 0, stream>>>(xc, w0t, rb0, A, cb);
        conv3x3_lds<0><<<cb * 8, 256, 0, stream>>>(A,  W1a, rb1a, nullptr, Bb, nullptr, cb);
        conv3x3_lds<1><<<cb * 8, 256, 0, stream>>>(Bb, W1b, rb1b, A, A, nullptr, cb);
        conv3x3_lds<0><<<cb * 8, 256, 0, stream>>>(A,  W2a, rb2a, nullptr, Bb, nullptr, cb);
        conv3x3_lds<2><<<cb * 8, 256, 0, stream>>>(Bb, W2b, rb2b, A, A, pool, cb);
        res_fc<<<cb, 64, 0, stream>>>(pool, rfc, rfb, flags + c0, out + (size_t)c0 * 10);
    }
}

// Round 19
// 620.035 us; speedup vs baseline: 1.1187x; 1.1187x over previous
//
#include <hip/hip_runtime.h>
#include <hip/hip_bf16.h>
#include <math.h>

#define BATCH 1024

typedef __attribute__((ext_vector_type(8))) short bf16x8;
typedef __attribute__((ext_vector_type(4))) float f32x4;

// Padded NHWC activation geometry, ci-chunk-major rows:
//   addr = img*IMG_B + row*ROW_B + chunk*CH_B + px*16
// (chunk = ci-group of 8 bf16; 34 px * 16 B = 544 B per chunk-plane; 8 planes/row)
#define IMG_ELEMS 73984
#define IMG_B 147968
#define ROW_B 4352            // 34 px * 128 B
#define CH_B 544              // 34 px * 16 B
#define WT_OFF 43520          // LDS offset of staged weights (after 10 act rows)
#define WT_HALF_B 36864       // one co-half weight image: 9 taps x 2 kb x 2 nt x 4 q x 16 m x 16 B

// ---------------- LeNet conv1 (3->6, 5x5 VALID) + ReLU + 2x2 maxpool ----------------
__global__ __launch_bounds__(256) void lenet_conv1(const float* __restrict__ x,
    const float* __restrict__ w, const float* __restrict__ bias, float* __restrict__ p1)
{
    __shared__ float img[3 * 1024];
    __shared__ float wl[450];
    __shared__ float bl[6];
    int b = blockIdx.x, t = threadIdx.x;
    for (int i = t; i < 3072; i += 256) img[i] = x[(size_t)b * 3072 + i];
    for (int i = t; i < 450; i += 256) wl[i] = w[i];
    if (t < 6) bl[t] = bias[t];
    __syncthreads();
    for (int idx = t; idx < 1176; idx += 256) {
        int o = idx / 196, r = idx - o * 196, py = r / 14, px = r - py * 14;
        int y0 = 2 * py, x0 = 2 * px;
        float s00, s01, s10, s11;
        s00 = s01 = s10 = s11 = bl[o];
        for (int c = 0; c < 3; c++) {
            float pv[6][6];
            #pragma unroll
            for (int i2 = 0; i2 < 6; i2++)
                #pragma unroll
                for (int j2 = 0; j2 < 6; j2++)
                    pv[i2][j2] = img[c * 1024 + (y0 + i2) * 32 + x0 + j2];
            const float* wc = &wl[o * 75 + c * 25];
            #pragma unroll
            for (int ky = 0; ky < 5; ky++)
                #pragma unroll
                for (int kx = 0; kx < 5; kx++) {
                    float wv = wc[ky * 5 + kx];
                    s00 += pv[ky][kx] * wv;
                    s01 += pv[ky][kx + 1] * wv;
                    s10 += pv[ky + 1][kx] * wv;
                    s11 += pv[ky + 1][kx + 1] * wv;
                }
        }
        float m = fmaxf(fmaxf(s00, s01), fmaxf(s10, s11));
        p1[(size_t)b * 1176 + idx] = fmaxf(m, 0.f);
    }
}

// ---------------- LeNet conv2 (6->16, 5x5 VALID) + ReLU + 2x2 maxpool ----------------
__global__ __launch_bounds__(256) void lenet_conv2(const float* __restrict__ p1,
    const float* __restrict__ w, const float* __restrict__ bias, float* __restrict__ p2)
{
    __shared__ float img[1176];
    __shared__ float wl[2400];
    __shared__ float bl[16];
    int b = blockIdx.x, t = threadIdx.x;
    for (int i = t; i < 1176; i += 256) img[i] = p1[(size_t)b * 1176 + i];
    for (int i = t; i < 2400; i += 256) wl[i] = w[i];
    if (t < 16) bl[t] = bias[t];
    __syncthreads();
    for (int idx = t; idx < 400; idx += 256) {
        int o = idx / 25, r = idx - o * 25, py = r / 5, px = r - py * 5;
        int y0 = 2 * py, x0 = 2 * px;
        float s00, s01, s10, s11;
        s00 = s01 = s10 = s11 = bl[o];
        for (int c = 0; c < 6; c++) {
            float pv[6][6];
            #pragma unroll
            for (int i2 = 0; i2 < 6; i2++)
                #pragma unroll
                for (int j2 = 0; j2 < 6; j2++)
                    pv[i2][j2] = img[c * 196 + (y0 + i2) * 14 + x0 + j2];
            const float* wc = &wl[o * 150 + c * 25];
            #pragma unroll
            for (int ky = 0; ky < 5; ky++)
                #pragma unroll
                for (int kx = 0; kx < 5; kx++) {
                    float wv = wc[ky * 5 + kx];
                    s00 += pv[ky][kx] * wv;
                    s01 += pv[ky][kx + 1] * wv;
                    s10 += pv[ky + 1][kx] * wv;
                    s11 += pv[ky + 1][kx + 1] * wv;
                }
        }
        float m = fmaxf(fmaxf(s00, s01), fmaxf(s10, s11));
        p2[(size_t)b * 400 + idx] = fmaxf(m, 0.f);
    }
}

// ---------------- LeNet FC head + argmax + conf-matrix + low-conf flag ----------------
__global__ __launch_bounds__(256) void lenet_fc(const float* __restrict__ p2,
    const float* __restrict__ w1, const float* __restrict__ b1,
    const float* __restrict__ w2, const float* __restrict__ b2,
    const float* __restrict__ w3, const float* __restrict__ b3,
    const int* __restrict__ labels, const float* __restrict__ thr,
    float* __restrict__ out, float* __restrict__ conf, int* __restrict__ flags)
{
    __shared__ float xin[400];
    __shared__ float h1[120];
    __shared__ float h2[84];
    __shared__ float ps[256];
    __shared__ float lg[10];
    int b = blockIdx.x, t = threadIdx.x;
    for (int i = t; i < 400; i += 256) xin[i] = p2[(size_t)b * 400 + i];
    __syncthreads();
    {
        int n = t & 127, half = t >> 7;
        float s = 0.f;
        if (n < 120) {
            int k0 = half * 200;
            for (int k = k0; k < k0 + 200; k++) s += xin[k] * w1[k * 120 + n];
        }
        ps[t] = s;
    }
    __syncthreads();
    if (t < 120) h1[t] = fmaxf(ps[t] + ps[t + 128] + b1[t], 0.f);
    __syncthreads();
    {
        int n = t & 127, half = t >> 7;
        float s = 0.f;
        if (n < 84) {
            int k0 = half * 60;
            for (int k = k0; k < k0 + 60; k++) s += h1[k] * w2[k * 84 + n];
        }
        ps[t] = s;
    }
    __syncthreads();
    if (t < 84) h2[t] = fmaxf(ps[t] + ps[t + 128] + b2[t], 0.f);
    __syncthreads();
    if (t < 10) {
        float s = b3[t];
        for (int k = 0; k < 84; k++) s += h2[k] * w3[k * 10 + t];
        lg[t] = s;
        out[(size_t)b * 10 + t] = s;
    }
    __syncthreads();
    if (t == 0) {
        int pred = 0;
        float m = lg[0];
        #pragma unroll
        for (int j = 1; j < 10; j++) if (lg[j] > m) { m = lg[j]; pred = j; }
        float se = 0.f, m2 = -1e30f;
        #pragma unroll
        for (int j = 0; j < 10; j++) {
            se += expf(lg[j] - m);
            if (j != pred) m2 = fmaxf(m2, lg[j]);
        }
        float gap = (1.f - expf(m2 - m)) / se;
        flags[b] = (gap <= thr[0]) ? 1 : 0;
        atomicAdd(&conf[labels[b] * 10 + pred], 1.f);
    }
}

// ---------------- weight prep: 4x OIHW fp32 -> bf16 LDS image [nh][tap][kb][nt][q][m][e] ----------------
__global__ __launch_bounds__(256) void prep_weights(
    const float* __restrict__ w0, const float* __restrict__ w1,
    const float* __restrict__ w2, const float* __restrict__ w3,
    __hip_bfloat16* __restrict__ dst)
{
    int tid = blockIdx.x * 256 + threadIdx.x;
    if (tid >= 4 * 36864) return;
    int c = tid / 36864, r = tid - c * 36864;
    int tap = r / 4096, r2 = r - tap * 4096;
    int co = r2 >> 6, ci = r2 & 63;
    const float* src = (c == 0) ? w0 : (c == 1) ? w1 : (c == 2) ? w2 : w3;
    float v = src[((size_t)co * 64 + ci) * 9 + tap];
    int nh = co >> 5, nt = (co >> 4) & 1, m = co & 15;
    int kb = ci >> 5, q = (ci >> 3) & 3, e = ci & 7;
    size_t elem = (size_t)(c * 2 + nh) * 18432
                + (size_t)((tap * 2 + kb) * 2 + nt) * 512 + q * 128 + m * 8 + e;
    dst[elem] = __float2bfloat16(v);
}

// ---------------- conv0 weight transpose: OIHW fp32 [64][3][3][3] -> [k 27][co 64] fp32 ----------------
__global__ __launch_bounds__(256) void prep_w0t(const float* __restrict__ w,
                                                float* __restrict__ dst)
{
    int tid = blockIdx.x * 256 + threadIdx.x;
    if (tid >= 1728) return;
    int k = tid >> 6, co = tid & 63;
    dst[tid] = w[co * 27 + k];
}

// ---------------- zero pad borders of [n] padded images (chunk-major layout) ----------------
__global__ __launch_bounds__(256) void zero_borders(__hip_bfloat16* __restrict__ buf, int n)
{
    int tid = blockIdx.x * 256 + threadIdx.x;
    int total = n * 132 * 8;
    if (tid >= total) return;
    int img = tid / 1056, r = tid - img * 1056;
    int pxi = r >> 3, chunk = r & 7;
    int row, col;
    if (pxi < 34)       { row = 0;  col = pxi; }
    else if (pxi < 68)  { row = 33; col = pxi - 34; }
    else if (pxi < 100) { row = pxi - 67; col = 0; }
    else                { row = pxi - 99; col = 33; }
    uint4 z = {0, 0, 0, 0};
    *(uint4*)((char*)buf + (size_t)img * IMG_B + (size_t)row * ROW_B
              + chunk * CH_B + col * 16) = z;
}

// ---------------- conv0: NCHW fp32 [3][32][32] -> padded chunk-major bf16, bias+ReLU ----------------
// r9-verified body; strip-fastest task order + bijective XCD swizzle (r17).
__global__ __launch_bounds__(256) void conv0_nhwc(const float* __restrict__ x,
    const float* __restrict__ wT, const float* __restrict__ bias,
    __hip_bfloat16* __restrict__ out, int cb)
{
    __shared__ char smem[8 * ROW_B];   // input tile (16320 B) then row bounce (34816 B)
    float* sl = (float*)smem;          // [3][10][34]
    int bid = blockIdx.x;
    int task = (bid & 7) * (gridDim.x >> 3) + (bid >> 3);   // bijective XCD swizzle
    int img = task >> 2, strip = task & 3;                  // strip fastest
    int r0 = strip * 8;
    int t = threadIdx.x;
    const float* xi = x + (size_t)img * 3072;
    for (int i = t; i < 1020; i += 256) {
        int c = i / 340, rr2 = i - c * 340;
        int rr = rr2 / 34, cc = rr2 - rr * 34;
        int y = r0 + rr - 1, xx = cc - 1;
        float v = 0.f;
        if (y >= 0 && y < 32 && xx >= 0 && xx < 32) v = xi[c * 1024 + y * 32 + xx];
        sl[(c * 10 + rr) * 34 + cc] = v;
    }
    __syncthreads();

    int rr = t >> 5, col = t & 31;
    float iv[27];
    #pragma unroll
    for (int c = 0; c < 3; c++)
        #pragma unroll
        for (int dy = 0; dy < 3; dy++)
            #pragma unroll
            for (int dx = 0; dx < 3; dx++)
                iv[c * 9 + dy * 3 + dx] = sl[(c * 10 + rr + dy) * 34 + col + dx];
    __syncthreads();   // all sl reads done; smem becomes the row bounce

    float s[64];
    #pragma unroll
    for (int co = 0; co < 64; co++) s[co] = bias[co];   // uniform s_load burst
    #pragma unroll
    for (int k = 0; k < 27; k++) {
        const float v = iv[k];
        const float* wk = wT + k * 64;                  // uniform -> s_load_dwordx16 x4
        #pragma unroll
        for (int co = 0; co < 64; co++) s[co] = fmaf(v, wk[co], s[co]);
    }
    __hip_bfloat16 ov[64];
    #pragma unroll
    for (int co = 0; co < 64; co++) ov[co] = __float2bfloat16(fmaxf(s[co], 0.f));

    // bounce: complete chunk-major rows (incl. pad cols as zeros)
    char* brow = smem + rr * ROW_B + (col + 1) * 16;
    const uint4* srcv = (const uint4*)ov;
    #pragma unroll
    for (int j = 0; j < 8; j++) *(uint4*)(brow + j * CH_B) = srcv[j];
    if (t < 128) {
        int row = t >> 4, ch = (t >> 1) & 7, side = t & 1;
        uint4 z = {0, 0, 0, 0};
        *(uint4*)(smem + row * ROW_B + ch * CH_B + (side ? 33 : 0) * 16) = z;
    }
    __syncthreads();
    // contiguous 34816-B store (rows r0+1 .. r0+8), fully line-covered
    char* gbase = (char*)out + (size_t)img * IMG_B + (size_t)(r0 + 1) * ROW_B;
    for (int u = t; u < 2176; u += 256)
        *(uint4*)(gbase + (size_t)u * 16) = *(const uint4*)(smem + (size_t)u * 16);
}

#define GLL(gp, lp)                                                            \
    __builtin_amdgcn_global_load_lds(                                          \
        (const __attribute__((address_space(1))) unsigned int*)(gp),           \
        (__attribute__((address_space(3))) unsigned int*)(lp), 16, 0, 0)

// ---------------- 3x3 SAME conv: LDS weights, SWAPPED MFMA, direct store ----------------
// r19 = r15/r17 conv body + MODE template:
//   MODE 0: plain conv+bias+relu | MODE 1: + skip-add | MODE 2: + skip-add +
//   fused avg-pool accumulate. r18's MODE-2 atomicAdd hammered 4 cache lines
//   16-way per image (83 us, +8 MB WRITE); r19 replaces it with CONTENTION-FREE
//   partial writes: after the m-lane shfl reduce, lane m==0 stores two float4
//   to the disjoint slot pool[img][strip][w][co] (every address written exactly
//   once -> no atomics, no memset). res_fc sums the 16 partials per co.
template<int MODE>
__global__ __launch_bounds__(256, 2) void conv3x3_lds(
    const __hip_bfloat16* __restrict__ act, const __hip_bfloat16* __restrict__ wts,
    const float* __restrict__ bias, const __hip_bfloat16* __restrict__ skip,
    __hip_bfloat16* __restrict__ out, float* __restrict__ pool, int cb)
{
    __shared__ char sl[WT_OFF + WT_HALF_B];   // 80384 B
    int bid = blockIdx.x;
    int task = (bid & 7) * (gridDim.x >> 3) + (bid >> 3);   // bijective XCD swizzle
    int img = task >> 3;
    int rem = task & 7;
    int strip = rem >> 1, nh = rem & 1;       // nh fastest: pair 2k/2k+1 adjacent
    int t = threadIdx.x;
    int w = t >> 6, lane = t & 63;
    int m = lane & 15, q = lane >> 4;

    // ---- stage 10 padded act rows (8s .. 8s+9), contiguous 43520 B ----
    const char* gsrc = (const char*)act + (size_t)img * IMG_B + (size_t)(strip * 8) * ROW_B;
    for (int u0 = w * 64; u0 < 2720; u0 += 256) {
        int u = u0 + lane;
        if (u < 2720)
            GLL(gsrc + (size_t)u * 16, sl + u0 * 16);
    }
    // ---- stage weight half, contiguous 36864 B (2304 units, exact) ----
    const char* gw = (const char*)wts + (size_t)nh * WT_HALF_B;
    for (int u0 = w * 64; u0 < 2304; u0 += 256)
        GLL(gw + (size_t)(u0 + lane) * 16, sl + WT_OFF + u0 * 16);
    __syncthreads();

    // ---- fragment base offsets (identical bytes to r9; roles swapped) ----
    int xbase[4];   // act frags (B-operand): nt -> row 2w+(nt>>1), px-half nt&1
    #pragma unroll
    for (int nt = 0; nt < 4; nt++)
        xbase[nt] = (2 * w + (nt >> 1)) * ROW_B + ((nt & 1) * 16 + m) * 16 + q * CH_B;
    int wbase[2];   // weight frags (A-operand): mt -> co block of 16
    #pragma unroll
    for (int mt = 0; mt < 2; mt++)
        wbase[mt] = WT_OFF + mt * 1024 + q * 256 + m * 16;

    f32x4 acc[2][4] = {};
    bf16x8 a[2][4], b[2][2];

    #define XLOAD(s, buf)                                                      \
        {                                                                      \
            const int tap_ = (s) >> 1, kb_ = (s) & 1;                          \
            const int off_ = (tap_ / 3) * ROW_B + (tap_ - (tap_ / 3) * 3) * 16 \
                           + kb_ * (4 * CH_B);                                 \
            _Pragma("unroll")                                                  \
            for (int nt = 0; nt < 4; nt++)                                     \
                a[buf][nt] = *(const bf16x8*)(sl + xbase[nt] + off_);          \
        }
    #define WLOAD(s, buf)                                                      \
        {                                                                      \
            const int off_ = ((s) >> 1) * 4096 + ((s) & 1) * 2048;             \
            _Pragma("unroll")                                                  \
            for (int mt = 0; mt < 2; mt++)                                     \
                b[buf][mt] = *(const bf16x8*)(sl + wbase[mt] + off_);          \
        }

    XLOAD(0, 0) WLOAD(0, 0)
    #pragma unroll
    for (int s = 0; s < 18; s++) {
        int cur = s & 1;
        if (s < 17) { XLOAD(s + 1, cur ^ 1) WLOAD(s + 1, cur ^ 1) }
        #pragma unroll
        for (int mt = 0; mt < 2; mt++)
            #pragma unroll
            for (int nt = 0; nt < 4; nt++)
                acc[mt][nt] = __builtin_amdgcn_mfma_f32_16x16x32_bf16(
                    b[cur][mt], a[cur][nt], acc[mt][nt], 0, 0, 0);
    }
    #undef XLOAD
    #undef WLOAD

    // ---- direct store: px = m + (nt&1)*16, co = nh*32 + mt*16 + q*4 + r ----
    // (r2-verified D layout; 4 consecutive co per lane = one aligned uint2)
    char* oimg = (char*)out + (size_t)img * IMG_B;
    const char* simg = (const char*)skip + (size_t)img * IMG_B;
    float4 bv4[2];
    #pragma unroll
    for (int mt = 0; mt < 2; mt++)
        bv4[mt] = *(const float4*)(bias + nh * 32 + mt * 16 + q * 4);

    size_t goff[2][4];
    #pragma unroll
    for (int mt = 0; mt < 2; mt++)
        #pragma unroll
        for (int nt = 0; nt < 4; nt++)
            goff[mt][nt] = (size_t)(strip * 8 + 1 + 2 * w + (nt >> 1)) * ROW_B
                         + (nh * 4 + 2 * mt + (q >> 1)) * CH_B
                         + (m + (nt & 1) * 16 + 1) * 16 + (q & 1) * 8;

    union { uint2 u; __hip_bfloat16 h[4]; } sk[2][4];
    if (MODE >= 1) {
        #pragma unroll
        for (int mt = 0; mt < 2; mt++)
            #pragma unroll
            for (int nt = 0; nt < 4; nt++)
                sk[mt][nt].u = *(const uint2*)(simg + goff[mt][nt]);
    }
    float psum[2][4];
    if (MODE == 2) {
        #pragma unroll
        for (int mt = 0; mt < 2; mt++)
            #pragma unroll
            for (int r = 0; r < 4; r++) psum[mt][r] = 0.f;
    }
    #pragma unroll
    for (int mt = 0; mt < 2; mt++) {
        #pragma unroll
        for (int nt = 0; nt < 4; nt++) {
            union { uint2 u; __hip_bfloat16 h[4]; } pk;
            #pragma unroll
            for (int r = 0; r < 4; r++) {
                float f = acc[mt][nt][r] + ((const float*)&bv4[mt])[r];
                if (MODE >= 1) f += __bfloat162float(sk[mt][nt].h[r]);
                f = fmaxf(f, 0.f);
                if (MODE == 2) psum[mt][r] += f;
                pk.h[r] = __float2bfloat16(f);
            }
            *(uint2*)(oimg + goff[mt][nt]) = pk.u;
        }
    }
    if (MODE == 2) {
        // reduce over the 16 m-lanes (covers all 32 px of this wave's 2 rows)
        #pragma unroll
        for (int mt = 0; mt < 2; mt++)
            #pragma unroll
            for (int r = 0; r < 4; r++) {
                float v = psum[mt][r];
                v += __shfl_xor(v, 1, 64);
                v += __shfl_xor(v, 2, 64);
                v += __shfl_xor(v, 4, 64);
                v += __shfl_xor(v, 8, 64);
                psum[mt][r] = v;
            }
        if (m == 0) {
            // disjoint slot: pool[((img*4+strip)*4+w)*64 + nh*32 + mt*16 + q*4 + r]
            float* pb = pool + (((size_t)img * 4 + strip) * 4 + w) * 64 + nh * 32 + q * 4;
            #pragma unroll
            for (int mt = 0; mt < 2; mt++) {
                float4 v4 = make_float4(psum[mt][0], psum[mt][1], psum[mt][2], psum[mt][3]);
                *(float4*)(pb + mt * 16) = v4;
            }
        }
    }
}

// ---------------- ResNet FC head: 16 partials/img -> mean -> FC, masked merge ----------------
__global__ __launch_bounds__(64) void res_fc(const float* __restrict__ pool,
    const float* __restrict__ rfc, const float* __restrict__ rfb,
    const int* __restrict__ flags, float* __restrict__ out)
{
    __shared__ float mns[64];
    int img = blockIdx.x, t = threadIdx.x;
    float s = 0.f;
    const float* pb = pool + (size_t)img * 1024 + t;
    #pragma unroll
    for (int i = 0; i < 16; i++) s += pb[i * 64];
    mns[t] = s * (1.f / 1024.f);
    __syncthreads();
    if (t < 10 && flags[img]) {
        float s2 = rfb[t];
        for (int c = 0; c < 64; c++) s2 += mns[c] * rfc[c * 10 + t];
        out[(size_t)img * 10 + t] = s2;
    }
}

extern "C" void kernel_launch(void* const* d_in, const int* in_sizes, int n_in,
                              void* d_out, int out_size, void* d_ws, size_t ws_size,
                              hipStream_t stream)
{
    const float* x    = (const float*)d_in[0];
    const float* thr  = (const float*)d_in[1];
    const int*   labels = (const int*)d_in[2];
    const float* lw1 = (const float*)d_in[3];  const float* lb1 = (const float*)d_in[4];
    const float* lw2 = (const float*)d_in[5];  const float* lb2 = (const float*)d_in[6];
    const float* lfc1 = (const float*)d_in[7]; const float* lfb1 = (const float*)d_in[8];
    const float* lfc2 = (const float*)d_in[9]; const float* lfb2 = (const float*)d_in[10];
    const float* lfc3 = (const float*)d_in[11];const float* lfb3 = (const float*)d_in[12];
    const float* rw0 = (const float*)d_in[13]; const float* rb0 = (const float*)d_in[14];
    const float* rw1a = (const float*)d_in[15];const float* rb1a = (const float*)d_in[16];
    const float* rw1b = (const float*)d_in[17];const float* rb1b = (const float*)d_in[18];
    const float* rw2a = (const float*)d_in[19];const float* rb2a = (const float*)d_in[20];
    const float* rw2b = (const float*)d_in[21];const float* rb2b = (const float*)d_in[22];
    const float* rfc = (const float*)d_in[23]; const float* rfb = (const float*)d_in[24];

    float* out  = (float*)d_out;
    float* conf = out + (size_t)BATCH * 10;

    int nc = 1;
    while (nc < 16 &&
           2ull * (size_t)(BATCH / nc) * 147968ull + 294912ull + 16384ull
               + (size_t)(BATCH / nc) * 4096ull > ws_size)
        nc <<= 1;
    int cb = BATCH / nc;

    __hip_bfloat16* A  = (__hip_bfloat16*)d_ws;
    __hip_bfloat16* Bb = A + (size_t)cb * IMG_ELEMS;
    __hip_bfloat16* wprep = Bb + (size_t)cb * IMG_ELEMS;
    int* flags = (int*)((char*)wprep + 294912);
    float* w0t = (float*)((char*)wprep + 294912 + 4096);
    float* pool = (float*)((char*)wprep + 294912 + 16384);   // cb*1024 floats

    float* p1 = (float*)A;
    float* p2 = p1 + 1204224;

    hipMemsetAsync(conf, 0, 100 * sizeof(float), stream);

    prep_weights<<<(4 * 36864 + 255) / 256, 256, 0, stream>>>(rw1a, rw1b, rw2a, rw2b, wprep);
    prep_w0t<<<7, 256, 0, stream>>>(rw0, w0t);

    lenet_conv1<<<BATCH, 256, 0, stream>>>(x, lw1, lb1, p1);
    lenet_conv2<<<BATCH, 256, 0, stream>>>(p1, lw2, lb2, p2);
    lenet_fc<<<BATCH, 256, 0, stream>>>(p2, lfc1, lfb1, lfc2, lfb2, lfc3, lfb3,
                                        labels, thr, out, conf, flags);

    // single call covers BOTH contiguous image buffers (A and Bb)
    int zb = (2 * cb * 1056 + 255) / 256;
    zero_borders<<<zb, 256, 0, stream>>>(A, 2 * cb);

    const __hip_bfloat16* W1a = wprep;
    const __hip_bfloat16* W1b = wprep + 36864;
    const __hip_bfloat16* W2a = wprep + 2 * 36864;
    const __hip_bfloat16* W2b = wprep + 3 * 36864;

    for (int c0 = 0; c0 < BATCH; c0 += cb) {
        const float* xc = x + (size_t)c0 * 3072;
        conv0_nhwc<<<cb * 4, 256, 0, stream>>>(xc, w0t, rb0, A, cb);
        conv3x3_lds<0><<<cb * 8, 256, 0, stream>>>(A,  W1a, rb1a, nullptr, Bb, nullptr, cb);
        conv3x3_lds<1><<<cb * 8, 256, 0, stream>>>(Bb, W1b, rb1b, A, A, nullptr, cb);
        conv3x3_lds<0><<<cb * 8, 256, 0, stream>>>(A,  W2a, rb2a, nullptr, Bb, nullptr, cb);
        conv3x3_lds<2><<<cb * 8, 256, 0, stream>>>(Bb, W2b, rb2b, A, A, pool, cb);
        res_fc<<<cb, 64, 0, stream>>>(pool, rfc, rfb, flags + c0, out + (size_t)c0 * 10);
    }
}

// Round 20
// 614.728 us; speedup vs baseline: 1.1284x; 1.0086x over previous
//
#include <hip/hip_runtime.h>
#include <hip/hip_bf16.h>
#include <math.h>

#define BATCH 1024

typedef __attribute__((ext_vector_type(8))) short bf16x8;
typedef __attribute__((ext_vector_type(4))) float f32x4;

// Padded NHWC activation geometry, ci-chunk-major rows:
//   addr = img*IMG_B + row*ROW_B + chunk*CH_B + px*16
// (chunk = ci-group of 8 bf16; 34 px * 16 B = 544 B per chunk-plane; 8 planes/row)
#define IMG_ELEMS 73984
#define IMG_B 147968
#define ROW_B 4352            // 34 px * 128 B
#define CH_B 544              // 34 px * 16 B
#define WT_OFF 43520          // LDS offset of staged weights (after 10 act rows)
#define WT_HALF_B 36864       // one co-half weight image: 9 taps x 2 kb x 2 nt x 4 q x 16 m x 16 B

// ---------------- LeNet conv1 (3->6, 5x5 VALID) + ReLU + 2x2 maxpool ----------------
__global__ __launch_bounds__(256) void lenet_conv1(const float* __restrict__ x,
    const float* __restrict__ w, const float* __restrict__ bias, float* __restrict__ p1)
{
    __shared__ float img[3 * 1024];
    __shared__ float wl[450];
    __shared__ float bl[6];
    int b = blockIdx.x, t = threadIdx.x;
    for (int i = t; i < 3072; i += 256) img[i] = x[(size_t)b * 3072 + i];
    for (int i = t; i < 450; i += 256) wl[i] = w[i];
    if (t < 6) bl[t] = bias[t];
    __syncthreads();
    for (int idx = t; idx < 1176; idx += 256) {
        int o = idx / 196, r = idx - o * 196, py = r / 14, px = r - py * 14;
        int y0 = 2 * py, x0 = 2 * px;
        float s00, s01, s10, s11;
        s00 = s01 = s10 = s11 = bl[o];
        for (int c = 0; c < 3; c++) {
            float pv[6][6];
            #pragma unroll
            for (int i2 = 0; i2 < 6; i2++)
                #pragma unroll
                for (int j2 = 0; j2 < 6; j2++)
                    pv[i2][j2] = img[c * 1024 + (y0 + i2) * 32 + x0 + j2];
            const float* wc = &wl[o * 75 + c * 25];
            #pragma unroll
            for (int ky = 0; ky < 5; ky++)
                #pragma unroll
                for (int kx = 0; kx < 5; kx++) {
                    float wv = wc[ky * 5 + kx];
                    s00 += pv[ky][kx] * wv;
                    s01 += pv[ky][kx + 1] * wv;
                    s10 += pv[ky + 1][kx] * wv;
                    s11 += pv[ky + 1][kx + 1] * wv;
                }
        }
        float m = fmaxf(fmaxf(s00, s01), fmaxf(s10, s11));
        p1[(size_t)b * 1176 + idx] = fmaxf(m, 0.f);
    }
}

// ---------------- LeNet conv2 (6->16, 5x5 VALID) + ReLU + 2x2 maxpool ----------------
__global__ __launch_bounds__(256) void lenet_conv2(const float* __restrict__ p1,
    const float* __restrict__ w, const float* __restrict__ bias, float* __restrict__ p2)
{
    __shared__ float img[1176];
    __shared__ float wl[2400];
    __shared__ float bl[16];
    int b = blockIdx.x, t = threadIdx.x;
    for (int i = t; i < 1176; i += 256) img[i] = p1[(size_t)b * 1176 + i];
    for (int i = t; i < 2400; i += 256) wl[i] = w[i];
    if (t < 16) bl[t] = bias[t];
    __syncthreads();
    for (int idx = t; idx < 400; idx += 256) {
        int o = idx / 25, r = idx - o * 25, py = r / 5, px = r - py * 5;
        int y0 = 2 * py, x0 = 2 * px;
        float s00, s01, s10, s11;
        s00 = s01 = s10 = s11 = bl[o];
        for (int c = 0; c < 6; c++) {
            float pv[6][6];
            #pragma unroll
            for (int i2 = 0; i2 < 6; i2++)
                #pragma unroll
                for (int j2 = 0; j2 < 6; j2++)
                    pv[i2][j2] = img[c * 196 + (y0 + i2) * 14 + x0 + j2];
            const float* wc = &wl[o * 150 + c * 25];
            #pragma unroll
            for (int ky = 0; ky < 5; ky++)
                #pragma unroll
                for (int kx = 0; kx < 5; kx++) {
                    float wv = wc[ky * 5 + kx];
                    s00 += pv[ky][kx] * wv;
                    s01 += pv[ky][kx + 1] * wv;
                    s10 += pv[ky + 1][kx] * wv;
                    s11 += pv[ky + 1][kx + 1] * wv;
                }
        }
        float m = fmaxf(fmaxf(s00, s01), fmaxf(s10, s11));
        p2[(size_t)b * 400 + idx] = fmaxf(m, 0.f);
    }
}

// ---------------- LeNet FC head + argmax + conf-matrix + low-conf flag ----------------
__global__ __launch_bounds__(256) void lenet_fc(const float* __restrict__ p2,
    const float* __restrict__ w1, const float* __restrict__ b1,
    const float* __restrict__ w2, const float* __restrict__ b2,
    const float* __restrict__ w3, const float* __restrict__ b3,
    const int* __restrict__ labels, const float* __restrict__ thr,
    float* __restrict__ out, float* __restrict__ conf, int* __restrict__ flags)
{
    __shared__ float xin[400];
    __shared__ float h1[120];
    __shared__ float h2[84];
    __shared__ float ps[256];
    __shared__ float lg[10];
    int b = blockIdx.x, t = threadIdx.x;
    for (int i = t; i < 400; i += 256) xin[i] = p2[(size_t)b * 400 + i];
    __syncthreads();
    {
        int n = t & 127, half = t >> 7;
        float s = 0.f;
        if (n < 120) {
            int k0 = half * 200;
            for (int k = k0; k < k0 + 200; k++) s += xin[k] * w1[k * 120 + n];
        }
        ps[t] = s;
    }
    __syncthreads();
    if (t < 120) h1[t] = fmaxf(ps[t] + ps[t + 128] + b1[t], 0.f);
    __syncthreads();
    {
        int n = t & 127, half = t >> 7;
        float s = 0.f;
        if (n < 84) {
            int k0 = half * 60;
            for (int k = k0; k < k0 + 60; k++) s += h1[k] * w2[k * 84 + n];
        }
        ps[t] = s;
    }
    __syncthreads();
    if (t < 84) h2[t] = fmaxf(ps[t] + ps[t + 128] + b2[t], 0.f);
    __syncthreads();
    if (t < 10) {
        float s = b3[t];
        for (int k = 0; k < 84; k++) s += h2[k] * w3[k * 10 + t];
        lg[t] = s;
        out[(size_t)b * 10 + t] = s;
    }
    __syncthreads();
    if (t == 0) {
        int pred = 0;
        float m = lg[0];
        #pragma unroll
        for (int j = 1; j < 10; j++) if (lg[j] > m) { m = lg[j]; pred = j; }
        float se = 0.f, m2 = -1e30f;
        #pragma unroll
        for (int j = 0; j < 10; j++) {
            se += expf(lg[j] - m);
            if (j != pred) m2 = fmaxf(m2, lg[j]);
        }
        float gap = (1.f - expf(m2 - m)) / se;
        flags[b] = (gap <= thr[0]) ? 1 : 0;
        atomicAdd(&conf[labels[b] * 10 + pred], 1.f);
    }
}

// ---------------- weight prep: 4x OIHW fp32 -> bf16 LDS image [nh][tap][kb][nt][q][m][e] ----------------
__global__ __launch_bounds__(256) void prep_weights(
    const float* __restrict__ w0, const float* __restrict__ w1,
    const float* __restrict__ w2, const float* __restrict__ w3,
    __hip_bfloat16* __restrict__ dst)
{
    int tid = blockIdx.x * 256 + threadIdx.x;
    if (tid >= 4 * 36864) return;
    int c = tid / 36864, r = tid - c * 36864;
    int tap = r / 4096, r2 = r - tap * 4096;
    int co = r2 >> 6, ci = r2 & 63;
    const float* src = (c == 0) ? w0 : (c == 1) ? w1 : (c == 2) ? w2 : w3;
    float v = src[((size_t)co * 64 + ci) * 9 + tap];
    int nh = co >> 5, nt = (co >> 4) & 1, m = co & 15;
    int kb = ci >> 5, q = (ci >> 3) & 3, e = ci & 7;
    size_t elem = (size_t)(c * 2 + nh) * 18432
                + (size_t)((tap * 2 + kb) * 2 + nt) * 512 + q * 128 + m * 8 + e;
    dst[elem] = __float2bfloat16(v);
}

// ---------------- conv0 weight transpose: OIHW fp32 [64][3][3][3] -> [k 27][co 64] fp32 ----------------
__global__ __launch_bounds__(256) void prep_w0t(const float* __restrict__ w,
                                                float* __restrict__ dst)
{
    int tid = blockIdx.x * 256 + threadIdx.x;
    if (tid >= 1728) return;
    int k = tid >> 6, co = tid & 63;
    dst[tid] = w[co * 27 + k];
}

// ---------------- zero pad borders of [n] padded images (chunk-major layout) ----------------
__global__ __launch_bounds__(256) void zero_borders(__hip_bfloat16* __restrict__ buf, int n)
{
    int tid = blockIdx.x * 256 + threadIdx.x;
    int total = n * 132 * 8;
    if (tid >= total) return;
    int img = tid / 1056, r = tid - img * 1056;
    int pxi = r >> 3, chunk = r & 7;
    int row, col;
    if (pxi < 34)       { row = 0;  col = pxi; }
    else if (pxi < 68)  { row = 33; col = pxi - 34; }
    else if (pxi < 100) { row = pxi - 67; col = 0; }
    else                { row = pxi - 99; col = 33; }
    uint4 z = {0, 0, 0, 0};
    *(uint4*)((char*)buf + (size_t)img * IMG_B + (size_t)row * ROW_B
              + chunk * CH_B + col * 16) = z;
}

// ---------------- conv0: NCHW fp32 [3][32][32] -> padded chunk-major bf16, bias+ReLU ----------------
// r9-verified body; strip-fastest task order + bijective XCD swizzle (r17).
__global__ __launch_bounds__(256) void conv0_nhwc(const float* __restrict__ x,
    const float* __restrict__ wT, const float* __restrict__ bias,
    __hip_bfloat16* __restrict__ out, int cb)
{
    __shared__ char smem[8 * ROW_B];   // input tile (16320 B) then row bounce (34816 B)
    float* sl = (float*)smem;          // [3][10][34]
    int bid = blockIdx.x;
    int task = (bid & 7) * (gridDim.x >> 3) + (bid >> 3);   // bijective XCD swizzle
    int img = task >> 2, strip = task & 3;                  // strip fastest
    int r0 = strip * 8;
    int t = threadIdx.x;
    const float* xi = x + (size_t)img * 3072;
    for (int i = t; i < 1020; i += 256) {
        int c = i / 340, rr2 = i - c * 340;
        int rr = rr2 / 34, cc = rr2 - rr * 34;
        int y = r0 + rr - 1, xx = cc - 1;
        float v = 0.f;
        if (y >= 0 && y < 32 && xx >= 0 && xx < 32) v = xi[c * 1024 + y * 32 + xx];
        sl[(c * 10 + rr) * 34 + cc] = v;
    }
    __syncthreads();

    int rr = t >> 5, col = t & 31;
    float iv[27];
    #pragma unroll
    for (int c = 0; c < 3; c++)
        #pragma unroll
        for (int dy = 0; dy < 3; dy++)
            #pragma unroll
            for (int dx = 0; dx < 3; dx++)
                iv[c * 9 + dy * 3 + dx] = sl[(c * 10 + rr + dy) * 34 + col + dx];
    __syncthreads();   // all sl reads done; smem becomes the row bounce

    float s[64];
    #pragma unroll
    for (int co = 0; co < 64; co++) s[co] = bias[co];   // uniform s_load burst
    #pragma unroll
    for (int k = 0; k < 27; k++) {
        const float v = iv[k];
        const float* wk = wT + k * 64;                  // uniform -> s_load_dwordx16 x4
        #pragma unroll
        for (int co = 0; co < 64; co++) s[co] = fmaf(v, wk[co], s[co]);
    }
    __hip_bfloat16 ov[64];
    #pragma unroll
    for (int co = 0; co < 64; co++) ov[co] = __float2bfloat16(fmaxf(s[co], 0.f));

    // bounce: complete chunk-major rows (incl. pad cols as zeros)
    char* brow = smem + rr * ROW_B + (col + 1) * 16;
    const uint4* srcv = (const uint4*)ov;
    #pragma unroll
    for (int j = 0; j < 8; j++) *(uint4*)(brow + j * CH_B) = srcv[j];
    if (t < 128) {
        int row = t >> 4, ch = (t >> 1) & 7, side = t & 1;
        uint4 z = {0, 0, 0, 0};
        *(uint4*)(smem + row * ROW_B + ch * CH_B + (side ? 33 : 0) * 16) = z;
    }
    __syncthreads();
    // contiguous 34816-B store (rows r0+1 .. r0+8), fully line-covered
    char* gbase = (char*)out + (size_t)img * IMG_B + (size_t)(r0 + 1) * ROW_B;
    for (int u = t; u < 2176; u += 256)
        *(uint4*)(gbase + (size_t)u * 16) = *(const uint4*)(smem + (size_t)u * 16);
}

#define GLL(gp, lp)                                                            \
    __builtin_amdgcn_global_load_lds(                                          \
        (const __attribute__((address_space(1))) unsigned int*)(gp),           \
        (__attribute__((address_space(3))) unsigned int*)(lp), 16, 0, 0)

// ---------------- 3x3 SAME conv: LDS weights, SWAPPED MFMA, direct store ----------------
// r20 = r19 + act-fragment reuse in the kloop. The old dy-major tap order read
// each (dx,kb) act fragment set 6 times (3 dy x 2 nt-rows) when only 4 rows are
// distinct. New order: (dx,kb)-outer / dy-inner with the 4-row x 2-px-half
// fragment set cached in registers (a[2][4][2], double-buffered across outer
// iterations) -> act LDS reads drop 72 -> 48 b128/kloop/wave (-33% traffic and
// conflicts). Weight prefetch ring unchanged (contiguous-1KB reads, no
// conflicts). fp32 accumulation order changes only rounding (tolerance-safe).
// MODE 0: conv+bias+relu | 1: +skip | 2: +skip +contention-free pool partials.
template<int MODE>
__global__ __launch_bounds__(256, 2) void conv3x3_lds(
    const __hip_bfloat16* __restrict__ act, const __hip_bfloat16* __restrict__ wts,
    const float* __restrict__ bias, const __hip_bfloat16* __restrict__ skip,
    __hip_bfloat16* __restrict__ out, float* __restrict__ pool, int cb)
{
    __shared__ char sl[WT_OFF + WT_HALF_B];   // 80384 B
    int bid = blockIdx.x;
    int task = (bid & 7) * (gridDim.x >> 3) + (bid >> 3);   // bijective XCD swizzle
    int img = task >> 3;
    int rem = task & 7;
    int strip = rem >> 1, nh = rem & 1;       // nh fastest: pair 2k/2k+1 adjacent
    int t = threadIdx.x;
    int w = t >> 6, lane = t & 63;
    int m = lane & 15, q = lane >> 4;

    // ---- stage 10 padded act rows (8s .. 8s+9), contiguous 43520 B ----
    const char* gsrc = (const char*)act + (size_t)img * IMG_B + (size_t)(strip * 8) * ROW_B;
    for (int u0 = w * 64; u0 < 2720; u0 += 256) {
        int u = u0 + lane;
        if (u < 2720)
            GLL(gsrc + (size_t)u * 16, sl + u0 * 16);
    }
    // ---- stage weight half, contiguous 36864 B (2304 units, exact) ----
    const char* gw = (const char*)wts + (size_t)nh * WT_HALF_B;
    for (int u0 = w * 64; u0 < 2304; u0 += 256)
        GLL(gw + (size_t)(u0 + lane) * 16, sl + WT_OFF + u0 * 16);
    __syncthreads();

    // ---- fragment base offsets ----
    int arow[4];    // act rows 2w .. 2w+3
    #pragma unroll
    for (int rr = 0; rr < 4; rr++) arow[rr] = (2 * w + rr) * ROW_B;
    int apx[2];     // px-half lane offset
    #pragma unroll
    for (int p = 0; p < 2; p++) apx[p] = ((p * 16 + m) * 16) + q * CH_B;
    int wbase[2];   // weight frags (A-operand): mt -> co block of 16
    #pragma unroll
    for (int mt = 0; mt < 2; mt++)
        wbase[mt] = WT_OFF + mt * 1024 + q * 256 + m * 16;

    f32x4 acc[2][4] = {};
    bf16x8 a[2][4][2], b[2][2];

    // outer o = dx*2 + kb (6 iters); inner dy (3) -> 18 MFMA steps total
    #define XLOAD8(o_, buf)                                                    \
        {                                                                      \
            const int dx_ = (o_) >> 1, kb_ = (o_) & 1;                         \
            const int off_ = dx_ * 16 + kb_ * (4 * CH_B);                      \
            _Pragma("unroll")                                                  \
            for (int rr = 0; rr < 4; rr++)                                     \
                _Pragma("unroll")                                              \
                for (int p = 0; p < 2; p++)                                    \
                    a[buf][rr][p] = *(const bf16x8*)(sl + arow[rr] + apx[p] + off_); \
        }
    #define WLOADS(s_, buf)                                                    \
        {                                                                      \
            const int o_ = (s_) / 3, dy_ = (s_) % 3;                           \
            const int dx_ = o_ >> 1, kb_ = o_ & 1;                             \
            const int off_ = (dy_ * 3 + dx_) * 4096 + kb_ * 2048;              \
            _Pragma("unroll")                                                  \
            for (int mt = 0; mt < 2; mt++)                                     \
                b[buf][mt] = *(const bf16x8*)(sl + wbase[mt] + off_);          \
        }

    XLOAD8(0, 0)
    WLOADS(0, 0)
    #pragma unroll
    for (int s = 0; s < 18; s++) {
        const int o = s / 3, dy = s % 3;
        const int ab = o & 1, wb = s & 1;
        if (dy == 0 && o < 5) XLOAD8(o + 1, ab ^ 1)
        if (s < 17) WLOADS(s + 1, wb ^ 1)
        #pragma unroll
        for (int mt = 0; mt < 2; mt++)
            #pragma unroll
            for (int nt = 0; nt < 4; nt++)
                acc[mt][nt] = __builtin_amdgcn_mfma_f32_16x16x32_bf16(
                    b[wb][mt], a[ab][(nt >> 1) + dy][nt & 1], acc[mt][nt], 0, 0, 0);
    }
    #undef XLOAD8
    #undef WLOADS

    // ---- direct store: px = m + (nt&1)*16, co = nh*32 + mt*16 + q*4 + r ----
    // (r2-verified D layout; 4 consecutive co per lane = one aligned uint2)
    char* oimg = (char*)out + (size_t)img * IMG_B;
    const char* simg = (const char*)skip + (size_t)img * IMG_B;
    float4 bv4[2];
    #pragma unroll
    for (int mt = 0; mt < 2; mt++)
        bv4[mt] = *(const float4*)(bias + nh * 32 + mt * 16 + q * 4);

    size_t goff[2][4];
    #pragma unroll
    for (int mt = 0; mt < 2; mt++)
        #pragma unroll
        for (int nt = 0; nt < 4; nt++)
            goff[mt][nt] = (size_t)(strip * 8 + 1 + 2 * w + (nt >> 1)) * ROW_B
                         + (nh * 4 + 2 * mt + (q >> 1)) * CH_B
                         + (m + (nt & 1) * 16 + 1) * 16 + (q & 1) * 8;

    union { uint2 u; __hip_bfloat16 h[4]; } sk[2][4];
    if (MODE >= 1) {
        #pragma unroll
        for (int mt = 0; mt < 2; mt++)
            #pragma unroll
            for (int nt = 0; nt < 4; nt++)
                sk[mt][nt].u = *(const uint2*)(simg + goff[mt][nt]);
    }
    float psum[2][4];
    if (MODE == 2) {
        #pragma unroll
        for (int mt = 0; mt < 2; mt++)
            #pragma unroll
            for (int r = 0; r < 4; r++) psum[mt][r] = 0.f;
    }
    #pragma unroll
    for (int mt = 0; mt < 2; mt++) {
        #pragma unroll
        for (int nt = 0; nt < 4; nt++) {
            union { uint2 u; __hip_bfloat16 h[4]; } pk;
            #pragma unroll
            for (int r = 0; r < 4; r++) {
                float f = acc[mt][nt][r] + ((const float*)&bv4[mt])[r];
                if (MODE >= 1) f += __bfloat162float(sk[mt][nt].h[r]);
                f = fmaxf(f, 0.f);
                if (MODE == 2) psum[mt][r] += f;
                pk.h[r] = __float2bfloat16(f);
            }
            *(uint2*)(oimg + goff[mt][nt]) = pk.u;
        }
    }
    if (MODE == 2) {
        // reduce over the 16 m-lanes (covers all 32 px of this wave's 2 rows)
        #pragma unroll
        for (int mt = 0; mt < 2; mt++)
            #pragma unroll
            for (int r = 0; r < 4; r++) {
                float v = psum[mt][r];
                v += __shfl_xor(v, 1, 64);
                v += __shfl_xor(v, 2, 64);
                v += __shfl_xor(v, 4, 64);
                v += __shfl_xor(v, 8, 64);
                psum[mt][r] = v;
            }
        if (m == 0) {
            // disjoint slot: pool[((img*4+strip)*4+w)*64 + nh*32 + mt*16 + q*4 + r]
            float* pb = pool + (((size_t)img * 4 + strip) * 4 + w) * 64 + nh * 32 + q * 4;
            #pragma unroll
            for (int mt = 0; mt < 2; mt++) {
                float4 v4 = make_float4(psum[mt][0], psum[mt][1], psum[mt][2], psum[mt][3]);
                *(float4*)(pb + mt * 16) = v4;
            }
        }
    }
}

// ---------------- ResNet FC head: 16 partials/img -> mean -> FC, masked merge ----------------
__global__ __launch_bounds__(64) void res_fc(const float* __restrict__ pool,
    const float* __restrict__ rfc, const float* __restrict__ rfb,
    const int* __restrict__ flags, float* __restrict__ out)
{
    __shared__ float mns[64];
    int img = blockIdx.x, t = threadIdx.x;
    float s = 0.f;
    const float* pb = pool + (size_t)img * 1024 + t;
    #pragma unroll
    for (int i = 0; i < 16; i++) s += pb[i * 64];
    mns[t] = s * (1.f / 1024.f);
    __syncthreads();
    if (t < 10 && flags[img]) {
        float s2 = rfb[t];
        for (int c = 0; c < 64; c++) s2 += mns[c] * rfc[c * 10 + t];
        out[(size_t)img * 10 + t] = s2;
    }
}

extern "C" void kernel_launch(void* const* d_in, const int* in_sizes, int n_in,
                              void* d_out, int out_size, void* d_ws, size_t ws_size,
                              hipStream_t stream)
{
    const float* x    = (const float*)d_in[0];
    const float* thr  = (const float*)d_in[1];
    const int*   labels = (const int*)d_in[2];
    const float* lw1 = (const float*)d_in[3];  const float* lb1 = (const float*)d_in[4];
    const float* lw2 = (const float*)d_in[5];  const float* lb2 = (const float*)d_in[6];
    const float* lfc1 = (const float*)d_in[7]; const float* lfb1 = (const float*)d_in[8];
    const float* lfc2 = (const float*)d_in[9]; const float* lfb2 = (const float*)d_in[10];
    const float* lfc3 = (const float*)d_in[11];const float* lfb3 = (const float*)d_in[12];
    const float* rw0 = (const float*)d_in[13]; const float* rb0 = (const float*)d_in[14];
    const float* rw1a = (const float*)d_in[15];const float* rb1a = (const float*)d_in[16];
    const float* rw1b = (const float*)d_in[17];const float* rb1b = (const float*)d_in[18];
    const float* rw2a = (const float*)d_in[19];const float* rb2a = (const float*)d_in[20];
    const float* rw2b = (const float*)d_in[21];const float* rb2b = (const float*)d_in[22];
    const float* rfc = (const float*)d_in[23]; const float* rfb = (const float*)d_in[24];

    float* out  = (float*)d_out;
    float* conf = out + (size_t)BATCH * 10;

    int nc = 1;
    while (nc < 16 &&
           2ull * (size_t)(BATCH / nc) * 147968ull + 294912ull + 16384ull
               + (size_t)(BATCH / nc) * 4096ull > ws_size)
        nc <<= 1;
    int cb = BATCH / nc;

    __hip_bfloat16* A  = (__hip_bfloat16*)d_ws;
    __hip_bfloat16* Bb = A + (size_t)cb * IMG_ELEMS;
    __hip_bfloat16* wprep = Bb + (size_t)cb * IMG_ELEMS;
    int* flags = (int*)((char*)wprep + 294912);
    float* w0t = (float*)((char*)wprep + 294912 + 4096);
    float* pool = (float*)((char*)wprep + 294912 + 16384);   // cb*1024 floats

    float* p1 = (float*)A;
    float* p2 = p1 + 1204224;

    hipMemsetAsync(conf, 0, 100 * sizeof(float), stream);

    prep_weights<<<(4 * 36864 + 255) / 256, 256, 0, stream>>>(rw1a, rw1b, rw2a, rw2b, wprep);
    prep_w0t<<<7, 256, 0, stream>>>(rw0, w0t);

    lenet_conv1<<<BATCH, 256, 0, stream>>>(x, lw1, lb1, p1);
    lenet_conv2<<<BATCH, 256, 0, stream>>>(p1, lw2, lb2, p2);
    lenet_fc<<<BATCH, 256, 0, stream>>>(p2, lfc1, lfb1, lfc2, lfb2, lfc3, lfb3,
                                        labels, thr, out, conf, flags);

    // single call covers BOTH contiguous image buffers (A and Bb)
    int zb = (2 * cb * 1056 + 255) / 256;
    zero_borders<<<zb, 256, 0, stream>>>(A, 2 * cb);

    const __hip_bfloat16* W1a = wprep;
    const __hip_bfloat16* W1b = wprep + 36864;
    const __hip_bfloat16* W2a = wprep + 2 * 36864;
    const __hip_bfloat16* W2b = wprep + 3 * 36864;

    for (int c0 = 0; c0 < BATCH; c0 += cb) {
        const float* xc = x + (size_t)c0 * 3072;
        conv0_nhwc<<<cb * 4, 256, 0, stream>>>(xc, w0t, rb0, A, cb);
        conv3x3_lds<0><<<cb * 8, 256, 0, stream>>>(A,  W1a, rb1a, nullptr, Bb, nullptr, cb);
        conv3x3_lds<1><<<cb * 8, 256, 0, stream>>>(Bb, W1b, rb1b, A, A, nullptr, cb);
        conv3x3_lds<0><<<cb * 8, 256, 0, stream>>>(A,  W2a, rb2a, nullptr, Bb, nullptr, cb);
        conv3x3_lds<2><<<cb * 8, 256, 0, stream>>>(Bb, W2b, rb2b, A, A, pool, cb);
        res_fc<<<cb, 64, 0, stream>>>(pool, rfc, rfb, flags + c0, out + (size_t)c0 * 10);
    }
}